// Round 1
// baseline (105.340 us; speedup 1.0000x reference)
//
#include <hip/hip_runtime.h>

#define EDIM 255   // tree node count (complete binary tree, 8 levels)
#define EPAD 256

__device__ __forceinline__ float wave_reduce_sum(float v) {
    #pragma unroll
    for (int off = 32; off > 0; off >>= 1) v += __shfl_xor(v, off, 64);
    return v;
}
__device__ __forceinline__ float wave_reduce_max(float v) {
    #pragma unroll
    for (int off = 32; off > 0; off >>= 1) v = fmaxf(v, __shfl_xor(v, off, 64));
    return v;
}

__global__ __launch_bounds__(256) void treewe_score_kernel(
    const int* __restrict__ x, const int* __restrict__ y,
    const float* __restrict__ emb, const float* __restrict__ w,
    float* __restrict__ out, int n_pairs)
{
    __shared__ float sm[4][EPAD];
    const int lane = threadIdx.x & 63;
    const int wv   = threadIdx.x >> 6;
    const int p    = blockIdx.x * 4 + wv;
    const bool active = p < n_pairs;

    float d[4];   // (xp - yp) for element e = 64*j + lane

    if (active) {
        const int rx = x[p];
        const int ry = y[p];
        const float* rowx = emb + (size_t)rx * EDIM;
        const float* rowy = emb + (size_t)ry * EDIM;

        float vx[4], vy[4];
        #pragma unroll
        for (int j = 0; j < 4; ++j) {
            const int e = 64 * j + lane;
            const bool in = (e < EDIM);
            vx[j] = in ? rowx[e] : -1e30f;
            vy[j] = in ? rowy[e] : -1e30f;
        }

        // softmax(x row)
        float mx = fmaxf(fmaxf(vx[0], vx[1]), fmaxf(vx[2], vx[3]));
        mx = wave_reduce_max(mx);
        float ex[4], sx = 0.f;
        #pragma unroll
        for (int j = 0; j < 4; ++j) { ex[j] = __expf(vx[j] - mx); sx += ex[j]; }
        sx = wave_reduce_sum(sx);
        const float ixs = 1.0f / sx;

        // softmax(y row)
        float my = fmaxf(fmaxf(vy[0], vy[1]), fmaxf(vy[2], vy[3]));
        my = wave_reduce_max(my);
        float ey[4], sy = 0.f;
        #pragma unroll
        for (int j = 0; j < 4; ++j) { ey[j] = __expf(vy[j] - my); sy += ey[j]; }
        sy = wave_reduce_sum(sy);
        const float iys = 1.0f / sy;

        // d = softmax_x - softmax_y  (subtree-sum is linear, so tree once)
        #pragma unroll
        for (int j = 0; j < 4; ++j) d[j] = ex[j] * ixs - ey[j] * iys;
        // e == 255 slot: both exps are 0 -> d = 0, safe filler for padded node.

        #pragma unroll
        for (int j = 0; j < 4; ++j) sm[wv][64 * j + lane] = d[j];
    }

    __syncthreads();

    // Bottom-up subtree sum in LDS: parents cnt = 64,32,...,1
    #pragma unroll
    for (int cnt = 64; cnt >= 1; cnt >>= 1) {
        if (active && lane < cnt) {
            const int q = (cnt - 1) + lane;          // parent node index
            sm[wv][q] += sm[wv][2 * q + 1] + sm[wv][2 * q + 2];
        }
        __syncthreads();
    }

    // score = -sum_i |tree_d[i] * w[i]|
    float part = 0.f;
    if (active) {
        #pragma unroll
        for (int j = 0; j < 4; ++j) {
            const int e = 64 * j + lane;
            if (e < EDIM) part += fabsf(sm[wv][e] * w[e]);
        }
    }
    part = wave_reduce_sum(part);
    if (active && lane == 0) out[p] = -part;
}

extern "C" void kernel_launch(void* const* d_in, const int* in_sizes, int n_in,
                              void* d_out, int out_size, void* d_ws, size_t ws_size,
                              hipStream_t stream) {
    const int*   x   = (const int*)d_in[0];
    const int*   y   = (const int*)d_in[1];
    const float* emb = (const float*)d_in[2];
    const float* w   = (const float*)d_in[3];
    float* out = (float*)d_out;

    const int n_pairs = in_sizes[0];           // 4096 * 50 = 204800
    const int blocks  = (n_pairs + 3) / 4;     // 4 pairs (waves) per block

    treewe_score_kernel<<<blocks, 256, 0, stream>>>(x, y, emb, w, out, n_pairs);
}

// Round 2
// 99.746 us; speedup vs baseline: 1.0561x; 1.0561x over previous
//
#include <hip/hip_runtime.h>

#define EDIM 255   // tree node count (complete binary tree, 8 levels)
#define EPAD 256

__device__ __forceinline__ float wave_reduce_sum(float v) {
    #pragma unroll
    for (int off = 32; off > 0; off >>= 1) v += __shfl_xor(v, off, 64);
    return v;
}
__device__ __forceinline__ float wave_reduce_max(float v) {
    #pragma unroll
    for (int off = 32; off > 0; off >>= 1) v = fmaxf(v, __shfl_xor(v, off, 64));
    return v;
}

// ---------------- Phase 1: per-row transform -------------------------------
// T[r] = tree_subtree_sum(softmax(emb[r])) * w   (linear tree-sum => per-pair
// difference of transforms equals transform of difference)
__global__ __launch_bounds__(256) void row_transform_kernel(
    const float* __restrict__ emb, const float* __restrict__ w,
    float* __restrict__ tr, int n_rows)
{
    __shared__ float sm[4][EPAD];
    const int lane = threadIdx.x & 63;
    const int wv   = threadIdx.x >> 6;
    const int r    = blockIdx.x * 4 + wv;
    const bool active = r < n_rows;

    if (active) {
        const float* row = emb + (size_t)r * EDIM;
        float v[4];
        #pragma unroll
        for (int j = 0; j < 4; ++j) {
            const int e = 64 * j + lane;
            v[j] = (e < EDIM) ? row[e] : -1e30f;
        }
        float m = wave_reduce_max(fmaxf(fmaxf(v[0], v[1]), fmaxf(v[2], v[3])));
        float s = 0.f;
        #pragma unroll
        for (int j = 0; j < 4; ++j) { v[j] = __expf(v[j] - m); s += v[j]; }
        s = wave_reduce_sum(s);
        const float is = 1.0f / s;
        #pragma unroll
        for (int j = 0; j < 4; ++j) sm[wv][64 * j + lane] = v[j] * is;
        // slot 255: exp(-1e30 - m) == 0 — safe pad, tree never reads it.
    }
    __syncthreads();

    // Bottom-up subtree sum: parents cnt = 64,32,...,1
    #pragma unroll
    for (int cnt = 64; cnt >= 1; cnt >>= 1) {
        if (active && lane < cnt) {
            const int q = (cnt - 1) + lane;
            sm[wv][q] += sm[wv][2 * q + 1] + sm[wv][2 * q + 2];
        }
        __syncthreads();
    }

    if (active) {
        float* o = tr + (size_t)r * EPAD;
        #pragma unroll
        for (int j = 0; j < 4; ++j) {
            const int e = 64 * j + lane;
            o[e] = (e < EDIM) ? sm[wv][e] * w[e] : 0.f;
        }
    }
}

// ---------------- Phase 2: per-pair weighted-L1 of transformed rows --------
__global__ __launch_bounds__(256) void pair_score_kernel(
    const int* __restrict__ x, const int* __restrict__ y,
    const float* __restrict__ tr, float* __restrict__ out, int n_pairs)
{
    const int lane = threadIdx.x & 63;
    const int wv   = threadIdx.x >> 6;
    const int p    = blockIdx.x * 4 + wv;
    if (p >= n_pairs) return;            // wave-uniform exit, no barriers here

    const float4* ax = (const float4*)(tr + (size_t)x[p] * EPAD);
    const float4* ay = (const float4*)(tr + (size_t)y[p] * EPAD);
    const float4 a = ax[lane];           // 64 lanes x 16 B = whole 1 KB row
    const float4 b = ay[lane];
    float s = fabsf(a.x - b.x) + fabsf(a.y - b.y)
            + fabsf(a.z - b.z) + fabsf(a.w - b.w);
    s = wave_reduce_sum(s);
    if (lane == 0) out[p] = -s;
}

// ---------------- Fallback: round-1 fused kernel (if ws too small) ---------
__global__ __launch_bounds__(256) void treewe_score_kernel(
    const int* __restrict__ x, const int* __restrict__ y,
    const float* __restrict__ emb, const float* __restrict__ w,
    float* __restrict__ out, int n_pairs)
{
    __shared__ float sm[4][EPAD];
    const int lane = threadIdx.x & 63;
    const int wv   = threadIdx.x >> 6;
    const int p    = blockIdx.x * 4 + wv;
    const bool active = p < n_pairs;

    if (active) {
        const float* rowx = emb + (size_t)x[p] * EDIM;
        const float* rowy = emb + (size_t)y[p] * EDIM;
        float vx[4], vy[4];
        #pragma unroll
        for (int j = 0; j < 4; ++j) {
            const int e = 64 * j + lane;
            const bool in = (e < EDIM);
            vx[j] = in ? rowx[e] : -1e30f;
            vy[j] = in ? rowy[e] : -1e30f;
        }
        float mx = wave_reduce_max(fmaxf(fmaxf(vx[0], vx[1]), fmaxf(vx[2], vx[3])));
        float ex[4], sx = 0.f;
        #pragma unroll
        for (int j = 0; j < 4; ++j) { ex[j] = __expf(vx[j] - mx); sx += ex[j]; }
        sx = wave_reduce_sum(sx);
        float my = wave_reduce_max(fmaxf(fmaxf(vy[0], vy[1]), fmaxf(vy[2], vy[3])));
        float ey[4], sy = 0.f;
        #pragma unroll
        for (int j = 0; j < 4; ++j) { ey[j] = __expf(vy[j] - my); sy += ey[j]; }
        sy = wave_reduce_sum(sy);
        const float ixs = 1.0f / sx, iys = 1.0f / sy;
        #pragma unroll
        for (int j = 0; j < 4; ++j)
            sm[wv][64 * j + lane] = ex[j] * ixs - ey[j] * iys;
    }
    __syncthreads();
    #pragma unroll
    for (int cnt = 64; cnt >= 1; cnt >>= 1) {
        if (active && lane < cnt) {
            const int q = (cnt - 1) + lane;
            sm[wv][q] += sm[wv][2 * q + 1] + sm[wv][2 * q + 2];
        }
        __syncthreads();
    }
    float part = 0.f;
    if (active) {
        #pragma unroll
        for (int j = 0; j < 4; ++j) {
            const int e = 64 * j + lane;
            if (e < EDIM) part += fabsf(sm[wv][e] * w[e]);
        }
    }
    part = wave_reduce_sum(part);
    if (active && lane == 0) out[p] = -part;
}

extern "C" void kernel_launch(void* const* d_in, const int* in_sizes, int n_in,
                              void* d_out, int out_size, void* d_ws, size_t ws_size,
                              hipStream_t stream) {
    const int*   x   = (const int*)d_in[0];
    const int*   y   = (const int*)d_in[1];
    const float* emb = (const float*)d_in[2];
    const float* w   = (const float*)d_in[3];
    float* out = (float*)d_out;

    const int n_pairs = in_sizes[0];               // 4096 * 50 = 204800
    const int n_rows  = in_sizes[2] / EDIM;        // 100000

    const size_t need = (size_t)n_rows * EPAD * sizeof(float);  // 102.4 MB
    if (ws_size >= need) {
        float* tr = (float*)d_ws;
        row_transform_kernel<<<(n_rows + 3) / 4, 256, 0, stream>>>(emb, w, tr, n_rows);
        pair_score_kernel<<<(n_pairs + 3) / 4, 256, 0, stream>>>(x, y, tr, out, n_pairs);
    } else {
        treewe_score_kernel<<<(n_pairs + 3) / 4, 256, 0, stream>>>(x, y, emb, w, out, n_pairs);
    }
}

// Round 3
// 90.923 us; speedup vs baseline: 1.1586x; 1.0970x over previous
//
#include <hip/hip_runtime.h>
#include <hip/hip_fp16.h>

#define EDIM 255   // tree node count (complete binary tree, 8 levels)
#define EPAD 256

__device__ __forceinline__ float wave_reduce_sum(float v) {
    #pragma unroll
    for (int off = 32; off > 0; off >>= 1) v += __shfl_xor(v, off, 64);
    return v;
}
__device__ __forceinline__ float wave_reduce_max(float v) {
    #pragma unroll
    for (int off = 32; off > 0; off >>= 1) v = fmaxf(v, __shfl_xor(v, off, 64));
    return v;
}

// ---------------- Phase 1: per-row transform + fp16 quantization -----------
// delta[r][e] = (tree_subtree_sum(softmax(emb[r]))[e] - s_e/255) * w[e]
// where s_e = subtree size (per-node constant, cancels in pair differences).
// Stored as fp16 * 2^k with per-row power-of-2 scale (exact dequant).
__global__ __launch_bounds__(256) void row_transform_q_kernel(
    const float* __restrict__ emb, const float* __restrict__ w,
    __half* __restrict__ tq, float* __restrict__ inv_scale, int n_rows)
{
    __shared__ float sm[4][EPAD];
    const int lane = threadIdx.x & 63;
    const int wv   = threadIdx.x >> 6;
    const int r    = blockIdx.x * 4 + wv;
    const bool active = r < n_rows;

    if (active) {
        const float* row = emb + (size_t)r * EDIM;
        float v[4];
        if (lane < 63) {                       // contiguous 16 B per lane
            const float4 t = *(const float4*)(row + 4 * lane);
            v[0] = t.x; v[1] = t.y; v[2] = t.z; v[3] = t.w;
        } else {                               // last lane: avoid OOB elem 255
            v[0] = row[252]; v[1] = row[253]; v[2] = row[254]; v[3] = -1e30f;
        }
        float m = wave_reduce_max(fmaxf(fmaxf(v[0], v[1]), fmaxf(v[2], v[3])));
        float s = 0.f;
        #pragma unroll
        for (int j = 0; j < 4; ++j) { v[j] = __expf(v[j] - m); s += v[j]; }
        s = wave_reduce_sum(s);
        const float is = 1.0f / s;
        #pragma unroll
        for (int j = 0; j < 4; ++j) sm[wv][4 * lane + j] = v[j] * is;
        // slot 255 holds exp(-1e30-m)=0 — safe pad, tree never reads it.
    }
    __syncthreads();

    // Bottom-up subtree sum: parents cnt = 64,32,...,1
    #pragma unroll
    for (int cnt = 64; cnt >= 1; cnt >>= 1) {
        if (active && lane < cnt) {
            const int q = (cnt - 1) + lane;
            sm[wv][q] += sm[wv][2 * q + 1] + sm[wv][2 * q + 2];
        }
        __syncthreads();
    }

    if (active) {
        float d[4];
        #pragma unroll
        for (int j = 0; j < 4; ++j) {
            const int e = 4 * lane + j;
            if (e < EDIM) {
                const int level = 31 - __clz(e + 1);           // floor(log2(e+1))
                const float sub = (float)((256 >> level) - 1); // subtree size
                d[j] = (sm[wv][e] - sub * (1.0f / 255.0f)) * w[e];
            } else d[j] = 0.f;
        }
        float amax = wave_reduce_max(fmaxf(fmaxf(fabsf(d[0]), fabsf(d[1])),
                                           fmaxf(fabsf(d[2]), fabsf(d[3]))));
        float scl, inv;
        if (amax > 0.f) {
            int ex; (void)frexpf(amax, &ex);   // amax = f * 2^ex, f in [0.5,1)
            scl = ldexpf(1.0f, 10 - ex);       // amax*scl in [512,1024)
            inv = ldexpf(1.0f, ex - 10);       // exact power-of-2 inverse
        } else { scl = 1.f; inv = 1.f; }

        __half2 q01 = __floats2half2_rn(d[0] * scl, d[1] * scl);
        __half2 q23 = __floats2half2_rn(d[2] * scl, d[3] * scl);
        float2 pack;                            // 8 B contiguous store per lane
        ((__half2*)&pack)[0] = q01;
        ((__half2*)&pack)[1] = q23;
        ((float2*)(tq + (size_t)r * EPAD))[lane] = pack;
        if (lane == 0) inv_scale[r] = inv;
    }
}

// ---------------- Phase 2: per-pair weighted-L1 of quantized rows ----------
__global__ __launch_bounds__(256) void pair_score_q_kernel(
    const int* __restrict__ x, const int* __restrict__ y,
    const __half* __restrict__ tq, const float* __restrict__ inv_scale,
    float* __restrict__ out, int n_pairs)
{
    const int lane = threadIdx.x & 63;
    const int wv   = threadIdx.x >> 6;
    const int p    = blockIdx.x * 4 + wv;
    if (p >= n_pairs) return;               // wave-uniform exit

    const int rx = x[p], ry = y[p];
    const float isx = inv_scale[rx];
    const float isy = inv_scale[ry];
    const float2 ra = ((const float2*)(tq + (size_t)rx * EPAD))[lane];  // 8 B
    const float2 rb = ((const float2*)(tq + (size_t)ry * EPAD))[lane];
    const __half2* ha = (const __half2*)&ra;
    const __half2* hb = (const __half2*)&rb;

    float s = 0.f;
    #pragma unroll
    for (int k = 0; k < 2; ++k) {
        const float2 fa = __half22float2(ha[k]);
        const float2 fb = __half22float2(hb[k]);
        s += fabsf(fa.x * isx - fb.x * isy) + fabsf(fa.y * isx - fb.y * isy);
    }
    s = wave_reduce_sum(s);
    if (lane == 0) out[p] = -s;
}

// ---------------- Fallback: round-1 fused kernel (if ws too small) ---------
__global__ __launch_bounds__(256) void treewe_score_kernel(
    const int* __restrict__ x, const int* __restrict__ y,
    const float* __restrict__ emb, const float* __restrict__ w,
    float* __restrict__ out, int n_pairs)
{
    __shared__ float sm[4][EPAD];
    const int lane = threadIdx.x & 63;
    const int wv   = threadIdx.x >> 6;
    const int p    = blockIdx.x * 4 + wv;
    const bool active = p < n_pairs;

    if (active) {
        const float* rowx = emb + (size_t)x[p] * EDIM;
        const float* rowy = emb + (size_t)y[p] * EDIM;
        float vx[4], vy[4];
        #pragma unroll
        for (int j = 0; j < 4; ++j) {
            const int e = 64 * j + lane;
            const bool in = (e < EDIM);
            vx[j] = in ? rowx[e] : -1e30f;
            vy[j] = in ? rowy[e] : -1e30f;
        }
        float mx = wave_reduce_max(fmaxf(fmaxf(vx[0], vx[1]), fmaxf(vx[2], vx[3])));
        float ex[4], sx = 0.f;
        #pragma unroll
        for (int j = 0; j < 4; ++j) { ex[j] = __expf(vx[j] - mx); sx += ex[j]; }
        sx = wave_reduce_sum(sx);
        float my = wave_reduce_max(fmaxf(fmaxf(vy[0], vy[1]), fmaxf(vy[2], vy[3])));
        float ey[4], sy = 0.f;
        #pragma unroll
        for (int j = 0; j < 4; ++j) { ey[j] = __expf(vy[j] - my); sy += ey[j]; }
        sy = wave_reduce_sum(sy);
        const float ixs = 1.0f / sx, iys = 1.0f / sy;
        #pragma unroll
        for (int j = 0; j < 4; ++j)
            sm[wv][64 * j + lane] = ex[j] * ixs - ey[j] * iys;
    }
    __syncthreads();
    #pragma unroll
    for (int cnt = 64; cnt >= 1; cnt >>= 1) {
        if (active && lane < cnt) {
            const int q = (cnt - 1) + lane;
            sm[wv][q] += sm[wv][2 * q + 1] + sm[wv][2 * q + 2];
        }
        __syncthreads();
    }
    float part = 0.f;
    if (active) {
        #pragma unroll
        for (int j = 0; j < 4; ++j) {
            const int e = 64 * j + lane;
            if (e < EDIM) part += fabsf(sm[wv][e] * w[e]);
        }
    }
    part = wave_reduce_sum(part);
    if (active && lane == 0) out[p] = -part;
}

extern "C" void kernel_launch(void* const* d_in, const int* in_sizes, int n_in,
                              void* d_out, int out_size, void* d_ws, size_t ws_size,
                              hipStream_t stream) {
    const int*   x   = (const int*)d_in[0];
    const int*   y   = (const int*)d_in[1];
    const float* emb = (const float*)d_in[2];
    const float* w   = (const float*)d_in[3];
    float* out = (float*)d_out;

    const int n_pairs = in_sizes[0];               // 4096 * 50 = 204800
    const int n_rows  = in_sizes[2] / EDIM;        // 100000

    const size_t tq_bytes = (size_t)n_rows * EPAD * sizeof(__half);  // 51.2 MB
    const size_t need     = tq_bytes + (size_t)n_rows * sizeof(float);
    if (ws_size >= need) {
        __half* tq        = (__half*)d_ws;
        float*  inv_scale = (float*)((char*)d_ws + tq_bytes);
        row_transform_q_kernel<<<(n_rows + 3) / 4, 256, 0, stream>>>(
            emb, w, tq, inv_scale, n_rows);
        pair_score_q_kernel<<<(n_pairs + 3) / 4, 256, 0, stream>>>(
            x, y, tq, inv_scale, out, n_pairs);
    } else {
        treewe_score_kernel<<<(n_pairs + 3) / 4, 256, 0, stream>>>(
            x, y, emb, w, out, n_pairs);
    }
}